// Round 14
// baseline (748.288 us; speedup 1.0000x reference)
//
#include <hip/hip_runtime.h>
#include <cstdint>

#pragma clang fp contract(off)

#define BS   128
#define NQ   900
#define NC   91
#define NQC  (NQ * NC)   // 81900
#define Q4   (NQC / 4)   // 20475
#define PRE  10000
#define POST 100
#define TBITS 13
#define TBINS (1 << TBITS)
#define TSHIFT (32 - TBITS)   // 19
#define CAPC 192              // per-class bucket cap (Binom(10000,1/91): mean 110, est max ~160)
#define ECAP 2048             // boundary-bin extract cap (expected ~128)

typedef unsigned long long ull;

__device__ __forceinline__ uint32_t fkey(float f) {
    uint32_t b = __float_as_uint(f);
    return (b & 0x80000000u) ? ~b : (b | 0x80000000u);
}
__device__ __forceinline__ float finv(uint32_t u) {
    uint32_t b = (u & 0x80000000u) ? (u & 0x7FFFFFFFu) : ~u;
    return __uint_as_float(b);
}
__device__ __forceinline__ uint32_t qclamp(uint32_t q) { return (q < NQ) ? q : (NQ - 1); }

__device__ __forceinline__ void cePair(ull& a, ull& b, bool desc) {
    ull mx = a > b ? a : b, mn = a < b ? a : b;
    a = desc ? mx : mn; b = desc ? mn : mx;
}
// in-lane bitonic compare-exchange via shuffle; element index e, step j (<64), stage k
__device__ __forceinline__ ull cmpexShfl(ull v, int j, int k, int e) {
    ull pv = __shfl_xor(v, j, 64);
    bool lower = (e & j) == 0;
    bool desc  = (e & k) == 0;
    bool keepMax = (lower == desc);
    return keepMax ? (v > pv ? v : pv) : (v < pv ? v : pv);
}

// ============ Single fused kernel: one block per image, no global workspace ============
// A1: 13-bit histogram -> boundary bin P (suffix>=PRE), C_above, K'. (rare 8-bit refine)
// A2: compact bin-P items to E (<=2048).  A3: O(n^2) rank-select -> exact 64-bit T64*
//     (global rank-PRE key incl. index tie-break; exactly PRE items have key64 >= T64*).
// B:  scatter key64>=T64* into 91 class buckets (LDS) + offD (max scaled coord + 1).
// C:  per-wave register bitonic-256 per class (desc; zeros pad tail) - no barriers.
// D:  per-class greedy NMS, one wave/class (registers+shuffles; suppressed items zeroed
//     in LDS). Cross-class suppression provably impossible (offset bands: inter<=area/4
//     => IoU<=1/3<0.7), so global greedy == per-class greedy; global pick order ==
//     survivors merged by key desc.
// E:  wave-0 tournament over 91 class heads emits first POST picks (exact order).
// F:  outputs (score=sigmoid(logit from key), class, raw scaled box).
__global__ void __launch_bounds__(1024) k_all(const float* __restrict__ logits,
                                              const float* __restrict__ pred_boxes,
                                              const float* __restrict__ target_sizes,
                                              float* __restrict__ out) {
    __shared__ __align__(16) unsigned char Bmem[NC * CAPC * 8];   // 139776 B
    __shared__ float4 shPB[NQ];                                   // 14400 B
    __shared__ uint32_t ccnt[NC];
    __shared__ ull pickkey[POST];
    __shared__ uint32_t smx[16];
    __shared__ float sOffD;
    __shared__ ull sT64;
    __shared__ uint32_t sP, sS, sKp, sInPref, sCab, sCtE;

    ull* B = (ull*)Bmem;
    uint32_t* HIST  = (uint32_t*)Bmem;                    // [0, 32768)  phase A1 only
    uint32_t* part  = (uint32_t*)(Bmem + 32768);          // [32768, 36864)
    uint32_t* part2 = (uint32_t*)(Bmem + 36864);          // 32 u32
    ull* E = (ull*)Bmem;                                  // [0, 16384) after HIST dead

    const int img = blockIdx.x;
    const int tid = threadIdx.x;
    const int lane = tid & 63;
    const int wave = tid >> 6;
    const float ih = target_sizes[img * 2 + 0];
    const float iw = target_sizes[img * 2 + 1];
    const float* lg = logits + (size_t)img * NQC;
    const float4* lg4 = (const float4*)lg;
    const float* pb = pred_boxes + (size_t)img * NQ * 4;

    // ---- A1: histogram + boundary-bin search ----
    for (int i = tid; i < TBINS; i += 1024) HIST[i] = 0u;
    if (tid == 0) { sCtE = 0u; sT64 = 0ull; }
    __syncthreads();
    for (int i = tid; i < Q4; i += 1024) {
        float4 v = lg4[i];
        atomicAdd(&HIST[fkey(v.x) >> TSHIFT], 1u);
        atomicAdd(&HIST[fkey(v.y) >> TSHIFT], 1u);
        atomicAdd(&HIST[fkey(v.z) >> TSHIFT], 1u);
        atomicAdd(&HIST[fkey(v.w) >> TSHIFT], 1u);
    }
    __syncthreads();
    {
        uint32_t s = 0;
        int base = tid * (TBINS / 1024);
        for (int j = 0; j < TBINS / 1024; ++j) s += HIST[base + j];
        part[tid] = s;
    }
    __syncthreads();
    if (tid < 32) {
        uint32_t s2 = 0;
        for (int j = 0; j < 32; ++j) s2 += part[tid * 32 + j];
        part2[tid] = s2;
    }
    __syncthreads();
    if (tid == 0) {
        uint32_t cum = 0; int w = 31;
        for (; w > 0; --w) { if (cum + part2[w] >= PRE) break; cum += part2[w]; }
        int t = w * 32 + 31;
        for (; t > w * 32; --t) { if (cum + part[t] >= PRE) break; cum += part[t]; }
        int b = t * (TBINS / 1024) + (TBINS / 1024 - 1);
        for (; b > t * (TBINS / 1024); --b) { if (cum + HIST[b] >= PRE) break; cum += HIST[b]; }
        sP = (uint32_t)b; sS = TSHIFT;
        sCab = cum;                    // count(ukey >= (P+1)<<S) < PRE
        sInPref = HIST[b];
        sKp = PRE - cum;               // 1..inPref: rank within prefix bin
    }
    __syncthreads();
    if (sInPref > ECAP) {   // rare block-uniform fallback: refine prefix by 8 bits
        uint32_t P = sP;
        for (int i = tid; i < 256; i += 1024) part[i] = 0u;
        __syncthreads();
        for (int i = tid; i < Q4; i += 1024) {
            float4 v = lg4[i];
            uint32_t u;
            u = fkey(v.x); if ((u >> TSHIFT) == P) atomicAdd(&part[(u >> (TSHIFT - 8)) & 0xFFu], 1u);
            u = fkey(v.y); if ((u >> TSHIFT) == P) atomicAdd(&part[(u >> (TSHIFT - 8)) & 0xFFu], 1u);
            u = fkey(v.z); if ((u >> TSHIFT) == P) atomicAdd(&part[(u >> (TSHIFT - 8)) & 0xFFu], 1u);
            u = fkey(v.w); if ((u >> TSHIFT) == P) atomicAdd(&part[(u >> (TSHIFT - 8)) & 0xFFu], 1u);
        }
        __syncthreads();
        if (tid == 0) {
            uint32_t K = sKp;
            uint32_t cum = 0; int x = 255;
            for (; x > 0; --x) { if (cum + part[x] >= K) break; cum += part[x]; }
            sP = (P << 8) | (uint32_t)x; sS = TSHIFT - 8;
            sCab += cum; sKp = K - cum; sInPref = part[x];
        }
        __syncthreads();
    }
    const uint32_t P = sP, S = sS;

    // ---- A2: compact prefix-bin items to E ----
    for (int i = tid; i < NQC; i += 1024) {
        uint32_t u = fkey(lg[i]);
        if ((u >> S) == P) {
            uint32_t s = atomicAdd(&sCtE, 1u);
            if (s < ECAP) E[s] = ((ull)u << 32) | (ull)(0xFFFFFFFFu - (uint32_t)i);
        }
    }
    __syncthreads();

    // ---- A3: rank-select K'-th largest in E (keys unique) ----
    {
        int nE = (int)sCtE; if (nE > ECAP) nE = ECAP;
        uint32_t Kp = sKp;
        ull m0 = (tid < nE) ? E[tid] : 0ull;
        ull m1 = (tid + 1024 < nE) ? E[tid + 1024] : 0ull;
        uint32_t c0 = 0, c1 = 0;
        for (int j = 0; j < nE; ++j) {
            ull ej = E[j];               // broadcast
            if (ej > m0) ++c0;
            if (ej > m1) ++c1;
        }
        if (tid < nE && c0 == Kp - 1) sT64 = m0;
        if (tid + 1024 < nE && c1 == Kp - 1) sT64 = m1;
    }
    __syncthreads();
    const ull T64 = sT64;

    // ---- B: class-bucket scatter of exactly the top-PRE set + offD ----
    for (int c = tid; c < NC; c += 1024) ccnt[c] = 0u;
    if (tid < NQ) shPB[tid] = ((const float4*)pb)[tid];
    __syncthreads();
    uint32_t lmx = 0u;
    for (int i = tid; i < Q4; i += 1024) {
        float4 v = lg4[i];
        #pragma unroll
        for (int c4 = 0; c4 < 4; ++c4) {
            float vv = (c4 == 0) ? v.x : (c4 == 1) ? v.y : (c4 == 2) ? v.z : v.w;
            uint32_t u = fkey(vv);
            uint32_t f = (uint32_t)(i * 4 + c4);
            ull k64 = ((ull)u << 32) | (ull)(0xFFFFFFFFu - f);
            if (k64 >= T64) {
                uint32_t q = f / NC;
                uint32_t c = f - q * NC;
                uint32_t s = atomicAdd(&ccnt[c], 1u);
                if (s < CAPC) B[c * CAPC + s] = k64;
                float4 bb = shPB[q];
                float x1 = (bb.x - 0.5f * bb.z) * iw;
                float y1 = (bb.y - 0.5f * bb.w) * ih;
                float x2 = (bb.x + 0.5f * bb.z) * iw;
                float y2 = (bb.y + 0.5f * bb.w) * ih;
                uint32_t km = fkey(fmaxf(fmaxf(x1, y1), fmaxf(x2, y2)));
                if (km > lmx) lmx = km;
            }
        }
    }
    for (int off = 32; off > 0; off >>= 1) {
        uint32_t o = (uint32_t)__shfl_down((int)lmx, off, 64);
        if (o > lmx) lmx = o;
    }
    if (lane == 0) smx[wave] = lmx;
    __syncthreads();
    if (tid == 0) {
        uint32_t m = smx[0];
        for (int w = 1; w < 16; ++w) if (smx[w] > m) m = smx[w];
        sOffD = finv(m) + 1.0f;   // max_coord + 1
    }
    __syncthreads();
    const float offD = sOffD;

    // ---- C: per-wave register bitonic-256 per class (desc; zeros sink to tail) ----
    for (int c = wave; c < NC; c += 16) {
        int n = (int)ccnt[c]; if (n > CAPC) n = CAPC;
        ull* L = &B[c * CAPC];
        ull v0 = (lane < n) ? L[lane] : 0ull;
        ull v1 = (lane + 64 < n) ? L[lane + 64] : 0ull;
        ull v2 = (lane + 128 < n) ? L[lane + 128] : 0ull;
        ull v3 = 0ull;
        for (int k = 2; k <= 256; k <<= 1) {
            for (int j = k >> 1; j > 0; j >>= 1) {
                if (j == 128) {
                    cePair(v0, v2, true);
                    cePair(v1, v3, true);
                } else if (j == 64) {
                    cePair(v0, v1, true);
                    cePair(v2, v3, (k & 128) == 0);
                } else {
                    v0 = cmpexShfl(v0, j, k, lane);
                    v1 = cmpexShfl(v1, j, k, lane + 64);
                    v2 = cmpexShfl(v2, j, k, lane + 128);
                    v3 = cmpexShfl(v3, j, k, lane + 192);
                }
            }
        }
        L[lane] = v0; L[lane + 64] = v1; L[lane + 128] = v2;
    }
    __syncthreads();

    // ---- D: per-class greedy NMS, one wave per class (registers + shuffles only) ----
    for (int c = wave; c < NC; c += 16) {
        int n = (int)ccnt[c]; if (n > CAPC) n = CAPC;
        if (n == 0) continue;
        ull* L = &B[c * CAPC];
        ull kk[3];
        kk[0] = (lane < n) ? L[lane] : 0ull;
        kk[1] = (lane + 64 < n) ? L[lane + 64] : 0ull;
        kk[2] = (lane + 128 < n) ? L[lane + 128] : 0ull;
        uint32_t alive = (kk[0] ? 1u : 0u) | (kk[1] ? 2u : 0u) | (kk[2] ? 4u : 0u);
        const float o = (float)c * offD;
        float ax1[3], ay1[3], ax2[3], ay2[3], aar[3];
        #pragma unroll
        for (int r = 0; r < 3; ++r) {
            uint32_t f = ~(uint32_t)kk[r];
            uint32_t q = qclamp(f / NC);
            float4 bb = shPB[q];
            float x1 = (bb.x - 0.5f * bb.z) * iw + o;
            float y1 = (bb.y - 0.5f * bb.w) * ih + o;
            float x2 = (bb.x + 0.5f * bb.z) * iw + o;
            float y2 = (bb.y + 0.5f * bb.w) * ih + o;
            ax1[r] = x1; ay1[r] = y1; ax2[r] = x2; ay2[r] = y2;
            aar[r] = (x2 - x1) * (y2 - y1);
        }
        while (true) {
            int mye = 999;
            if (alive & 1u) mye = lane;
            else if (alive & 2u) mye = lane + 64;
            else if (alive & 4u) mye = lane + 128;
            int h = mye;
            for (int off = 32; off > 0; off >>= 1) {
                int ot = __shfl_xor(h, off, 64);
                if (ot < h) h = ot;
            }
            if (h == 999) break;           // wave-uniform
            int hl = h & 63, hr = h >> 6;  // uniform
            float px1, py1, px2, py2, par;
            if (hr == 0)      { px1 = ax1[0]; py1 = ay1[0]; px2 = ax2[0]; py2 = ay2[0]; par = aar[0]; }
            else if (hr == 1) { px1 = ax1[1]; py1 = ay1[1]; px2 = ax2[1]; py2 = ay2[1]; par = aar[1]; }
            else              { px1 = ax1[2]; py1 = ay1[2]; px2 = ax2[2]; py2 = ay2[2]; par = aar[2]; }
            px1 = __shfl(px1, hl, 64); py1 = __shfl(py1, hl, 64);
            px2 = __shfl(px2, hl, 64); py2 = __shfl(py2, hl, 64);
            par = __shfl(par, hl, 64);
            if (lane == hl) alive &= ~(1u << hr);   // picked: survivor, not re-pickable
            #pragma unroll
            for (int r = 0; r < 3; ++r) {
                if (alive & (1u << r)) {
                    float xx1 = fmaxf(px1, ax1[r]);
                    float yy1 = fmaxf(py1, ay1[r]);
                    float xx2 = fminf(px2, ax2[r]);
                    float yy2 = fminf(py2, ay2[r]);
                    float inter = fmaxf(xx2 - xx1, 0.0f) * fmaxf(yy2 - yy1, 0.0f);
                    float uni = (par + aar[r]) - inter;
                    float iou = inter / fmaxf(uni, 1e-9f);
                    if (!(iou <= 0.7f)) {
                        alive &= ~(1u << r);
                        L[lane + 64 * r] = 0ull;    // suppressed: dead for tournament
                    }
                }
            }
        }
    }
    __syncthreads();

    // ---- E: wave-0 tournament over 91 class heads -> picks in exact global order ----
    if (wave == 0) {
        int c0 = lane, c1 = lane + 64;
        int n0 = (c0 < NC) ? ((ccnt[c0] < CAPC) ? (int)ccnt[c0] : CAPC) : 0;
        int n1 = (c1 < NC) ? ((ccnt[c1] < CAPC) ? (int)ccnt[c1] : CAPC) : 0;
        int p0 = 0, p1 = 0;
        ull firstKey = 0ull;
        for (int p = 0; p < POST; ++p) {
            ull k0 = 0ull;
            while (p0 < n0) { k0 = B[c0 * CAPC + p0]; if (k0) break; ++p0; }
            if (p0 >= n0) k0 = 0ull;
            ull k1 = 0ull;
            while (p1 < n1) { k1 = B[c1 * CAPC + p1]; if (k1) break; ++p1; }
            if (p1 >= n1) k1 = 0ull;
            ull best = (k0 >= k1) ? k0 : k1;
            int bc = (k0 >= k1) ? 0 : 1;
            ull bk = best; int bl = lane;
            for (int off = 32; off > 0; off >>= 1) {
                ull ok = __shfl_xor(bk, off, 64);
                int ol = __shfl_xor(bl, off, 64);
                if (ok > bk) { bk = ok; bl = ol; }
            }
            if (p == 0) firstKey = bk;      // uniform; total items = PRE > 0 so bk != 0 here
            if (bk == 0ull) {               // survivors exhausted: reference repeats rank-0 item
                if (lane == 0) for (int pp = p; pp < POST; ++pp) pickkey[pp] = firstKey;
                break;
            }
            if (lane == bl) {
                pickkey[p] = bk;
                if (bc == 0) ++p0; else ++p1;
            }
        }
    }
    __syncthreads();

    // ---- F: outputs ----
    if (tid < POST) {
        ull key = pickkey[tid];
        uint32_t f = ~(uint32_t)key;
        uint32_t q = qclamp(f / NC);
        uint32_t c = f - (f / NC) * NC;
        float4 bb = shPB[q];
        float rx1 = (bb.x - 0.5f * bb.z) * iw;
        float ry1 = (bb.y - 0.5f * bb.w) * ih;
        float rx2 = (bb.x + 0.5f * bb.z) * iw;
        float ry2 = (bb.y + 0.5f * bb.w) * ih;
        float score = 1.0f / (1.0f + expf(-finv((uint32_t)(key >> 32))));
        out[img * POST + tid] = score;
        out[BS * POST + img * POST + tid] = (float)(c % NC);
        float* ob = out + 2 * BS * POST + ((size_t)img * POST + tid) * 4;
        ob[0] = rx1; ob[1] = ry1; ob[2] = rx2; ob[3] = ry2;
    }
}

extern "C" void kernel_launch(void* const* d_in, const int* in_sizes, int n_in,
                              void* d_out, int out_size, void* d_ws, size_t ws_size,
                              hipStream_t stream) {
    const float* logits = (const float*)d_in[0];
    const float* boxes  = (const float*)d_in[1];
    const float* tsizes = (const float*)d_in[2];
    float* out = (float*)d_out;
    (void)d_ws; (void)ws_size;

    k_all<<<BS, 1024, 0, stream>>>(logits, boxes, tsizes, out);
}